// Round 8
// baseline (293.789 us; speedup 1.0000x reference)
//
#include <hip/hip_runtime.h>
#include <hip/hip_bf16.h>
#include <math.h>
#include <type_traits>

// MoE: E=16, D=H=768, T=6304 tokens; fp32 in/out, bf16 internally for MFMA.
// R8: register prefetch depth 2 in expert_gemm (loads issued 2 K-iters ahead;
//     vmcnt wait at store_tiles now covers ~2 iterations of latency).
//     Gate v3 (Wg in LDS), XCD expert grouping, staged epilogue unchanged.
#define T_TOK 6304
#define DMODEL 768
#define NEXP 16
#define NGATE 394            // 6304 / 16 tokens per gate unit

typedef __bf16 bf16x8 __attribute__((ext_vector_type(8)));
typedef float f32x4 __attribute__((ext_vector_type(4)));

__device__ __forceinline__ unsigned short f2bf(float f) {
    __hip_bfloat16 b = __float2bfloat16(f);   // RNE
    return __builtin_bit_cast(unsigned short, b);
}
__device__ __forceinline__ unsigned int pack2(float lo, float hi) {
    return (unsigned int)f2bf(lo) | ((unsigned int)f2bf(hi) << 16);
}

// ---------- gate v3: 394 blocks, 16 tokens/block, Wg in LDS -------------------------
__global__ __launch_bounds__(256) void gate_kernel(
    const float* __restrict__ x, const float* __restrict__ Wg,
    const float* __restrict__ bg, int* __restrict__ cnt, int* __restrict__ list,
    unsigned short* __restrict__ xb)
{
    __shared__ __align__(16) float wlds[16][772];   // 49,408 B; stride 772 words
    __shared__ double lg[16][17];
    const int tid = threadIdx.x;
    {   // Wg -> LDS: 3072 float4, 12 per thread
        const float4* src = (const float4*)Wg;
#pragma unroll
        for (int v = tid, it = 0; it < 12; ++it, v += 256) {
            float4 wv = src[v];
            int row = v / 192, col = (v - row * 192) * 4;   // 192 float4 per row
            *(float4*)&wlds[row][col] = wv;
        }
    }
    __syncthreads();

    const int tt = tid >> 4;
    const int e  = tid & 15;
    const int t  = blockIdx.x * 16 + tt;     // 6304 = 394*16
    const float4* xr = (const float4*)(x + (size_t)t * DMODEL);
    double s0 = 0, s1 = 0, s2 = 0, s3 = 0;
#pragma unroll 8
    for (int i = 0; i < DMODEL / 4; ++i) {
        float4 a = xr[i];
        float4 w = *(const float4*)&wlds[e][i * 4];
        s0 += (double)a.x * (double)w.x;
        s1 += (double)a.y * (double)w.y;
        s2 += (double)a.z * (double)w.z;
        s3 += (double)a.w * (double)w.w;
    }
    lg[tt][e] = (s0 + s1) + (s2 + s3);
    if (xb) {   // emit x row slice [e*48, e*48+48) as bf16 (L1-hot re-read)
        uint4* dst = (uint4*)(xb + (size_t)t * DMODEL + e * 48);
#pragma unroll
        for (int u = 0; u < 6; ++u) {
            float4 a = xr[e * 12 + 2 * u], b = xr[e * 12 + 2 * u + 1];
            dst[u] = make_uint4(pack2(a.x, a.y), pack2(a.z, a.w),
                                pack2(b.x, b.y), pack2(b.z, b.w));
        }
    }
    __syncthreads();
    if (e == 0) {   // strict first-max argmax (np semantics)
        double best = -1e300; int bi = 0;
#pragma unroll
        for (int k = 0; k < NEXP; ++k) {
            double v = lg[tt][k] + (double)bg[k];
            if (v > best) { best = v; bi = k; }
        }
        int pos = atomicAdd(&cnt[bi], 1);
        list[bi * T_TOK + pos] = t;
    }
}

// ---------- gathered expert GEMM: (192,8) + XCD grouping + depth-2 prefetch ---------
// BM=BN=BK=64, 4 waves, wave tile 32x32, double-buffered LDS, 1 barrier per K-iter.
// Depth-2 register pipeline: K(j) loaded at iter j-2, ds_written at end of iter j-1,
// consumed by MFMA in iter j. Two NAMED register sets (A/B) + manual 2-step unroll
// keep all indexing compile-time (no scratch).
// SWAPPED MFMA: D col = lane&15 = token, D row = (lane>>4)*4+reg = weight col.
// Epilogue staged via LDS: 4 adjacent lanes cover one row's 128/256B contiguously.
template<int GELU, int PACKED_IN, int PACKED_OUT, typename TW, typename TOUT>
__global__ __launch_bounds__(256, 4) void expert_gemm(
    const unsigned short* __restrict__ in, const TW* __restrict__ Wb,
    const float* __restrict__ bias, const int* __restrict__ cnt,
    const int* __restrict__ list, TOUT* __restrict__ outp)
{
    constexpr int BK = 64, LDK = 72;   // pad 72: 144B row stride, 2-way alias (free)
    constexpr int NIT = DMODEL / BK;   // 12 (even)
    constexpr bool W_F32 = std::is_same<TW, float>::value;
    __shared__ __align__(16) unsigned short At[2][64][LDK];
    __shared__ __align__(16) unsigned short Bt[2][64][LDK];
    __shared__ int toks[64];

    const int bx = blockIdx.x;              // expert-grouped XCD swizzle
    const int g  = bx >> 3;                 // 0..23: group within XCD
    const int e  = (bx & 7) + 8 * (g / 12); // expert; e%8 == bx%8 == XCD
    const int nb = g % 12;                  // column block
    const int c = cnt[e];
    int off = 0;
    if (PACKED_IN || PACKED_OUT)
        for (int k = 0; k < e; ++k) off += cnt[k];   // prefix base of expert e
    const int n0 = nb * 64;
    const int tid = threadIdx.x, lane = tid & 63, w = tid >> 6;
    const int rg = w & 1, cgp = w >> 1;
    const int l15 = lane & 15, q8 = (lane >> 4) * 8, q = lane >> 4;
    const int sr = tid >> 2, sk = (tid & 3) * 16;

    const TW* bsrc = Wb + (size_t)e * DMODEL * DMODEL + (size_t)(n0 + sr) * DMODEL + sk;
    const int* lst = list + e * T_TOK;

    for (int yt = blockIdx.y; yt * 64 < c; yt += 8) {
        const int m0 = yt * 64;
        __syncthreads();                     // prior y-iter epilogue done (LDS reuse)
        if (!PACKED_OUT && tid < 64) {
            int mi = m0 + tid;
            toks[tid] = lst[mi < c ? mi : c - 1];
        }
        const int ma0 = m0 + sr;
        const int mac = ma0 < c ? ma0 : c - 1;
        const unsigned short* asrc = PACKED_IN
            ? in + (size_t)(off + mac) * DMODEL + sk
            : in + (size_t)lst[mac] * DMODEL + sk;

        f32x4 acc[2][2];
#pragma unroll
        for (int i = 0; i < 2; ++i)
#pragma unroll
            for (int j = 0; j < 2; ++j) acc[i][j] = (f32x4){0.f, 0.f, 0.f, 0.f};

        // two named register sets (compile-time indexed; rule #20)
        uint4 paA[2], paB[2];
        float4 fbA[4], fbB[4];
        uint4 pbA[2], pbB[2];

        auto load_set = [&](uint4* pa_, float4* fb_, uint4* pb_, int k0) {
            const uint4* s = (const uint4*)(asrc + k0);
            pa_[0] = s[0]; pa_[1] = s[1];
            if constexpr (W_F32) {
                const float4* t2 = (const float4*)(bsrc + k0);
                fb_[0] = t2[0]; fb_[1] = t2[1]; fb_[2] = t2[2]; fb_[3] = t2[3];
            } else {
                const uint4* t2 = (const uint4*)(bsrc + k0);
                pb_[0] = t2[0]; pb_[1] = t2[1];
            }
        };
        auto store_set = [&](int buf, const uint4* pa_, const float4* fb_,
                             const uint4* pb_) {
            *(uint4*)&At[buf][sr][sk] = pa_[0]; *(uint4*)&At[buf][sr][sk + 8] = pa_[1];
            if constexpr (W_F32) {
                uint4 w0, w1;
                w0.x = pack2(fb_[0].x, fb_[0].y); w0.y = pack2(fb_[0].z, fb_[0].w);
                w0.z = pack2(fb_[1].x, fb_[1].y); w0.w = pack2(fb_[1].z, fb_[1].w);
                w1.x = pack2(fb_[2].x, fb_[2].y); w1.y = pack2(fb_[2].z, fb_[2].w);
                w1.z = pack2(fb_[3].x, fb_[3].y); w1.w = pack2(fb_[3].z, fb_[3].w);
                *(uint4*)&Bt[buf][sr][sk] = w0; *(uint4*)&Bt[buf][sr][sk + 8] = w1;
            } else {
                *(uint4*)&Bt[buf][sr][sk] = pb_[0]; *(uint4*)&Bt[buf][sr][sk + 8] = pb_[1];
            }
        };
        auto mfma_step = [&](int buf) {
#pragma unroll
            for (int kk = 0; kk < BK; kk += 32) {
                bf16x8 a0 = *(const bf16x8*)&At[buf][rg * 32 + l15][kk + q8];
                bf16x8 a1 = *(const bf16x8*)&At[buf][rg * 32 + 16 + l15][kk + q8];
                bf16x8 b0 = *(const bf16x8*)&Bt[buf][cgp * 32 + l15][kk + q8];
                bf16x8 b1 = *(const bf16x8*)&Bt[buf][cgp * 32 + 16 + l15][kk + q8];
                acc[0][0] = __builtin_amdgcn_mfma_f32_16x16x32_bf16(b0, a0, acc[0][0], 0, 0, 0);
                acc[0][1] = __builtin_amdgcn_mfma_f32_16x16x32_bf16(b1, a0, acc[0][1], 0, 0, 0);
                acc[1][0] = __builtin_amdgcn_mfma_f32_16x16x32_bf16(b0, a1, acc[1][0], 0, 0, 0);
                acc[1][1] = __builtin_amdgcn_mfma_f32_16x16x32_bf16(b1, a1, acc[1][1], 0, 0, 0);
            }
        };

        // prologue: K0 -> setA, K1 -> setB; ds_write K0 into buf0
        load_set(paA, fbA, pbA, 0);
        load_set(paB, fbB, pbB, BK);
        store_set(0, paA, fbA, pbA);

        // main loop, 2 K-iters per pass; set indexing fully static
#pragma unroll 1
        for (int it = 0; it < NIT; it += 2) {
            // even iter `it`: compute buf0; prefetch K(it+2) -> setA (freed last pass)
            __syncthreads();                 // buf0 ready
            if (it + 2 < NIT) load_set(paA, fbA, pbA, (it + 2) * BK);
            mfma_step(0);
            store_set(1, paB, fbB, pbB);     // K(it+1) -> buf1 (always valid: it+1<NIT)
            // odd iter `it+1`: compute buf1; prefetch K(it+3) -> setB
            __syncthreads();                 // buf1 ready
            if (it + 3 < NIT) load_set(paB, fbB, pbB, (it + 3) * BK);
            mfma_step(1);
            if (it + 2 < NIT) store_set(0, paA, fbA, pbA);   // K(it+2) -> buf0
        }

        // ---- staged epilogue: acc(+bias,+GELU) -> LDS C -> full-line stores
        __syncthreads();                     // all MFMA LDS reads done; overlay At
        float (*C)[68] = reinterpret_cast<float (*)[68]>(&At[0][0][0]);  // 17.4KB
#pragma unroll
        for (int i = 0; i < 2; ++i) {
            const int mrow = rg * 32 + i * 16 + l15;
#pragma unroll
            for (int j = 0; j < 2; ++j) {
                const int lc = cgp * 32 + j * 16 + q * 4;
                const float4 bv = *(const float4*)&bias[e * DMODEL + n0 + lc];
                float v0 = acc[i][j][0] + bv.x;
                float v1 = acc[i][j][1] + bv.y;
                float v2 = acc[i][j][2] + bv.z;
                float v3 = acc[i][j][3] + bv.w;
                if (GELU) {
                    v0 = 0.5f * v0 * (1.f + erff(v0 * 0.70710678118654752f));
                    v1 = 0.5f * v1 * (1.f + erff(v1 * 0.70710678118654752f));
                    v2 = 0.5f * v2 * (1.f + erff(v2 * 0.70710678118654752f));
                    v3 = 0.5f * v3 * (1.f + erff(v3 * 0.70710678118654752f));
                }
                *(float4*)&C[mrow][lc] = make_float4(v0, v1, v2, v3);
            }
        }
        __syncthreads();
        {   // thread -> (row, 16-col segment): 4 adjacent lanes cover a row contiguously
            const int row = tid >> 2, q2 = tid & 3;
            if (m0 + row < c) {
                const size_t rb = PACKED_OUT
                    ? (size_t)(off + m0 + row) * DMODEL
                    : (size_t)toks[row] * DMODEL;
                const int cg0 = q2 * 16;
                const float* cr = &C[row][cg0];
                if constexpr (std::is_same<TOUT, float>::value) {
                    float4* dst = (float4*)&outp[rb + n0 + cg0];
                    dst[0] = *(const float4*)&cr[0];
                    dst[1] = *(const float4*)&cr[4];
                    dst[2] = *(const float4*)&cr[8];
                    dst[3] = *(const float4*)&cr[12];
                } else {
                    uint4* dst = (uint4*)&outp[rb + n0 + cg0];
                    dst[0] = make_uint4(pack2(cr[0], cr[1]),  pack2(cr[2], cr[3]),
                                        pack2(cr[4], cr[5]),  pack2(cr[6], cr[7]));
                    dst[1] = make_uint4(pack2(cr[8], cr[9]),  pack2(cr[10], cr[11]),
                                        pack2(cr[12], cr[13]), pack2(cr[14], cr[15]));
                }
            }
        }
    }
}

// ---------- legacy small-workspace kernel (proven, fp32 A input) --------------------
template<int GELU, typename TA, typename TW, typename TOUT>
__global__ __launch_bounds__(256, 4) void expert_layer(
    const TA* __restrict__ in, const TW* __restrict__ W,
    const float* __restrict__ bias, const int* __restrict__ cnt,
    const int* __restrict__ list, TOUT* __restrict__ outp)
{
    constexpr int BK = 64, LDK = 72;
    constexpr bool A_F32 = std::is_same<TA, float>::value;
    constexpr bool W_F32 = std::is_same<TW, float>::value;
    __shared__ __align__(16) unsigned short At[2][64][LDK];
    __shared__ __align__(16) unsigned short Bt[2][64][LDK];
    __shared__ int toks[64];

    const int bx = blockIdx.x;
    const int e = bx / 12, nb = bx % 12;
    const int c = cnt[e];
    const int n0 = nb * 64;
    const int tid = threadIdx.x, lane = tid & 63, w = tid >> 6;
    const int rg = w & 1, cgp = w >> 1;
    const int l15 = lane & 15, q8 = (lane >> 4) * 8, q = lane >> 4;
    const int sr = tid >> 2, sk = (tid & 3) * 16;

    const TW* bsrc = W + (size_t)e * DMODEL * DMODEL + (size_t)(n0 + sr) * DMODEL + sk;
    const int* lst = list + e * T_TOK;

    uint4 pa[2], pb[2];
    float4 fa[4], fb[4];

    for (int yt = blockIdx.y; yt * 64 < c; yt += 8) {
        const int m0 = yt * 64;
        __syncthreads();
        if (tid < 64) {
            int mi = m0 + tid;
            toks[tid] = lst[mi < c ? mi : c - 1];
        }
        int ma = m0 + sr;
        const TA* asrc = in + (size_t)lst[ma < c ? ma : c - 1] * DMODEL + sk;

        f32x4 acc[2][2];
#pragma unroll
        for (int i = 0; i < 2; ++i)
#pragma unroll
            for (int j = 0; j < 2; ++j) acc[i][j] = (f32x4){0.f, 0.f, 0.f, 0.f};

        auto load_regs = [&](int k0) {
            if constexpr (A_F32) {
                const float4* s = (const float4*)(asrc + k0);
                fa[0] = s[0]; fa[1] = s[1]; fa[2] = s[2]; fa[3] = s[3];
            } else {
                const uint4* s = (const uint4*)(asrc + k0);
                pa[0] = s[0]; pa[1] = s[1];
            }
            if constexpr (W_F32) {
                const float4* s = (const float4*)(bsrc + k0);
                fb[0] = s[0]; fb[1] = s[1]; fb[2] = s[2]; fb[3] = s[3];
            } else {
                const uint4* s = (const uint4*)(bsrc + k0);
                pb[0] = s[0]; pb[1] = s[1];
            }
        };
        auto store_tiles = [&](int buf) {
            if constexpr (A_F32) {
                uint4 w0, w1;
                w0.x = pack2(fa[0].x, fa[0].y); w0.y = pack2(fa[0].z, fa[0].w);
                w0.z = pack2(fa[1].x, fa[1].y); w0.w = pack2(fa[1].z, fa[1].w);
                w1.x = pack2(fa[2].x, fa[2].y); w1.y = pack2(fa[2].z, fa[2].w);
                w1.z = pack2(fa[3].x, fa[3].y); w1.w = pack2(fa[3].z, fa[3].w);
                *(uint4*)&At[buf][sr][sk] = w0; *(uint4*)&At[buf][sr][sk + 8] = w1;
            } else {
                *(uint4*)&At[buf][sr][sk] = pa[0]; *(uint4*)&At[buf][sr][sk + 8] = pa[1];
            }
            if constexpr (W_F32) {
                uint4 w0, w1;
                w0.x = pack2(fb[0].x, fb[0].y); w0.y = pack2(fb[0].z, fb[0].w);
                w0.z = pack2(fb[1].x, fb[1].y); w0.w = pack2(fb[1].z, fb[1].w);
                w1.x = pack2(fb[2].x, fb[2].y); w1.y = pack2(fb[2].z, fb[2].w);
                w1.z = pack2(fb[3].x, fb[3].y); w1.w = pack2(fb[3].z, fb[3].w);
                *(uint4*)&Bt[buf][sr][sk] = w0; *(uint4*)&Bt[buf][sr][sk + 8] = w1;
            } else {
                *(uint4*)&Bt[buf][sr][sk] = pb[0]; *(uint4*)&Bt[buf][sr][sk + 8] = pb[1];
            }
        };

        load_regs(0);
        store_tiles(0);
#pragma unroll 1
        for (int it = 0; it < DMODEL / BK; ++it) {
            __syncthreads();
            if (it + 1 < DMODEL / BK) load_regs((it + 1) * BK);
            const int buf = it & 1;
#pragma unroll
            for (int kk = 0; kk < BK; kk += 32) {
                bf16x8 a0 = *(const bf16x8*)&At[buf][rg * 32 + l15][kk + q8];
                bf16x8 a1 = *(const bf16x8*)&At[buf][rg * 32 + 16 + l15][kk + q8];
                bf16x8 b0 = *(const bf16x8*)&Bt[buf][cgp * 32 + l15][kk + q8];
                bf16x8 b1 = *(const bf16x8*)&Bt[buf][cgp * 32 + 16 + l15][kk + q8];
                acc[0][0] = __builtin_amdgcn_mfma_f32_16x16x32_bf16(a0, b0, acc[0][0], 0, 0, 0);
                acc[0][1] = __builtin_amdgcn_mfma_f32_16x16x32_bf16(a0, b1, acc[0][1], 0, 0, 0);
                acc[1][0] = __builtin_amdgcn_mfma_f32_16x16x32_bf16(a1, b0, acc[1][0], 0, 0, 0);
                acc[1][1] = __builtin_amdgcn_mfma_f32_16x16x32_bf16(a1, b1, acc[1][1], 0, 0, 0);
            }
            if (it + 1 < DMODEL / BK) store_tiles(buf ^ 1);
        }

#pragma unroll
        for (int i = 0; i < 2; ++i) {
#pragma unroll
            for (int j = 0; j < 2; ++j) {
                int col = n0 + cgp * 32 + j * 16 + l15;
                float bv = bias[e * DMODEL + col];
#pragma unroll
                for (int r = 0; r < 4; ++r) {
                    int mrow = rg * 32 + i * 16 + q * 4 + r;
                    if (m0 + mrow < c) {
                        float val = acc[i][j][r] + bv;
                        if (GELU) val = 0.5f * val * (1.f + erff(val * 0.70710678118654752f));
                        size_t idx = (size_t)toks[mrow] * DMODEL + col;
                        if constexpr (std::is_same<TOUT, float>::value) outp[idx] = val;
                        else outp[idx] = f2bf(val);
                    }
                }
            }
        }
    }
}

// ---------- launch ------------------------------------------------------------------
extern "C" void kernel_launch(void* const* d_in, const int* in_sizes, int n_in,
                              void* d_out, int out_size, void* d_ws, size_t ws_size,
                              hipStream_t stream)
{
    const float* x  = (const float*)d_in[0];
    const float* W1 = (const float*)d_in[1];
    const float* b1 = (const float*)d_in[2];
    const float* W2 = (const float*)d_in[3];
    const float* b2 = (const float*)d_in[4];
    const float* Wg = (const float*)d_in[5];
    const float* bg = (const float*)d_in[6];
    float* out = (float*)d_out;

    char* ws   = (char*)d_ws;
    int*  cnt  = (int*)ws;                                  // 64 B
    int*  list = (int*)(ws + 256);                          // 403,456 B
    unsigned short* xb  = (unsigned short*)(ws + 403712);   // 9,682,944 B
    unsigned short* h   = (unsigned short*)(ws + 10086656); // 9,682,944 B
    const bool big = ws_size >= (size_t)19769600;

    hipMemsetAsync(cnt, 0, 256, stream);
    dim3 grid(12 * NEXP, 8);   // 192 x 8; persistent y-stride, no dead blocks
    if (big) {
        gate_kernel<<<dim3(NGATE), dim3(256), 0, stream>>>(
            x, Wg, bg, cnt, list, xb);
        // L1: gathered bf16 x @ fp32 W1 (in-reg convert) -> packed bf16 h
        expert_gemm<1, 0, 1, float, unsigned short>
            <<<grid, dim3(256), 0, stream>>>(xb, W1, b1, cnt, list, h);
        // L2: packed bf16 h @ fp32 W2 (in-reg convert) -> scattered fp32 out
        expert_gemm<0, 1, 0, float, float>
            <<<grid, dim3(256), 0, stream>>>(h, W2, b2, cnt, list, out);
    } else {   // fallback: fp32 A input with fused bf16 staging (proven path)
        gate_kernel<<<dim3(NGATE), dim3(256), 0, stream>>>(
            x, Wg, bg, cnt, list, nullptr);
        expert_layer<1, float, float, unsigned short>
            <<<grid, dim3(256), 0, stream>>>(x, W1, b1, cnt, list, h);
        expert_layer<0, unsigned short, float, float>
            <<<grid, dim3(256), 0, stream>>>(h, W2, b2, cnt, list, out);
    }
}

// Round 9
// 268.155 us; speedup vs baseline: 1.0956x; 1.0956x over previous
//
#include <hip/hip_runtime.h>
#include <hip/hip_bf16.h>
#include <math.h>
#include <type_traits>

// MoE: E=16, D=H=768, T=6304 tokens; fp32 in/out, bf16 internally for MFMA.
// R9: BM=128 tile in expert_gemm (wave tile 64x32, acc 4x2, y-split 4).
//     Halves block count and barrier-stalls per unit output (m93: 64->128 = 1.51x).
//     R8 depth-2 prefetch REVERTED (raised L2 pressure: FETCH +25%, WRITE +75%).
//     Gate v3 (Wg in LDS), XCD expert grouping, staged full-line epilogue kept.
#define T_TOK 6304
#define DMODEL 768
#define NEXP 16
#define NGATE 394            // 6304 / 16 tokens per gate unit

typedef __bf16 bf16x8 __attribute__((ext_vector_type(8)));
typedef float f32x4 __attribute__((ext_vector_type(4)));

__device__ __forceinline__ unsigned short f2bf(float f) {
    __hip_bfloat16 b = __float2bfloat16(f);   // RNE
    return __builtin_bit_cast(unsigned short, b);
}
__device__ __forceinline__ unsigned int pack2(float lo, float hi) {
    return (unsigned int)f2bf(lo) | ((unsigned int)f2bf(hi) << 16);
}

// ---------- gate v3: 394 blocks, 16 tokens/block, Wg in LDS -------------------------
__global__ __launch_bounds__(256) void gate_kernel(
    const float* __restrict__ x, const float* __restrict__ Wg,
    const float* __restrict__ bg, int* __restrict__ cnt, int* __restrict__ list,
    unsigned short* __restrict__ xb)
{
    __shared__ __align__(16) float wlds[16][772];   // 49,408 B; stride 772 words
    __shared__ double lg[16][17];
    const int tid = threadIdx.x;
    {   // Wg -> LDS: 3072 float4, 12 per thread
        const float4* src = (const float4*)Wg;
#pragma unroll
        for (int v = tid, it = 0; it < 12; ++it, v += 256) {
            float4 wv = src[v];
            int row = v / 192, col = (v - row * 192) * 4;   // 192 float4 per row
            *(float4*)&wlds[row][col] = wv;
        }
    }
    __syncthreads();

    const int tt = tid >> 4;
    const int e  = tid & 15;
    const int t  = blockIdx.x * 16 + tt;     // 6304 = 394*16
    const float4* xr = (const float4*)(x + (size_t)t * DMODEL);
    double s0 = 0, s1 = 0, s2 = 0, s3 = 0;
#pragma unroll 8
    for (int i = 0; i < DMODEL / 4; ++i) {
        float4 a = xr[i];
        float4 w = *(const float4*)&wlds[e][i * 4];
        s0 += (double)a.x * (double)w.x;
        s1 += (double)a.y * (double)w.y;
        s2 += (double)a.z * (double)w.z;
        s3 += (double)a.w * (double)w.w;
    }
    lg[tt][e] = (s0 + s1) + (s2 + s3);
    if (xb) {   // emit x row slice [e*48, e*48+48) as bf16 (L1-hot re-read)
        uint4* dst = (uint4*)(xb + (size_t)t * DMODEL + e * 48);
#pragma unroll
        for (int u = 0; u < 6; ++u) {
            float4 a = xr[e * 12 + 2 * u], b = xr[e * 12 + 2 * u + 1];
            dst[u] = make_uint4(pack2(a.x, a.y), pack2(a.z, a.w),
                                pack2(b.x, b.y), pack2(b.z, b.w));
        }
    }
    __syncthreads();
    if (e == 0) {   // strict first-max argmax (np semantics)
        double best = -1e300; int bi = 0;
#pragma unroll
        for (int k = 0; k < NEXP; ++k) {
            double v = lg[tt][k] + (double)bg[k];
            if (v > best) { best = v; bi = k; }
        }
        int pos = atomicAdd(&cnt[bi], 1);
        list[bi * T_TOK + pos] = t;
    }
}

// ---------- gathered expert GEMM: BM=128 x BN=64 x BK=64, XCD grouping --------------
// 4 waves, wave tile 64x32 (acc[4][2]), double-buffered LDS, 1 barrier per K-iter.
// bx swizzle: bx = (e%8) + 8*(nb + 12*(e/8)); grid (192,4); 2 blocks/CU (56KB LDS).
// A = bf16 (xb or packed h). W: fp32 -> bf16 in-reg during LDS staging.
// SWAPPED MFMA: D col = lane&15 = token, D row = (lane>>4)*4+reg = weight col.
// Epilogue staged via LDS C[128][68]: 2 adjacent lanes cover one row contiguously.
template<int GELU, int PACKED_IN, int PACKED_OUT, typename TW, typename TOUT>
__global__ __launch_bounds__(256, 2) void expert_gemm(
    const unsigned short* __restrict__ in, const TW* __restrict__ Wb,
    const float* __restrict__ bias, const int* __restrict__ cnt,
    const int* __restrict__ list, TOUT* __restrict__ outp)
{
    constexpr int BM = 128, BK = 64, LDK = 72;  // pad 72: 144B stride, 2-way alias
    constexpr int NIT = DMODEL / BK;            // 12
    constexpr bool W_F32 = std::is_same<TW, float>::value;
    __shared__ __align__(16) unsigned short At[2][BM][LDK];   // 36,864 B
    __shared__ __align__(16) unsigned short Bt[2][64][LDK];   // 18,432 B
    __shared__ int toks[BM];

    const int bx = blockIdx.x;              // expert-grouped XCD swizzle
    const int g  = bx >> 3;                 // 0..23: group within XCD
    const int e  = (bx & 7) + 8 * (g / 12); // expert; e%8 == bx%8 == XCD
    const int nb = g % 12;                  // column block
    const int c = cnt[e];
    int off = 0;
    if (PACKED_IN || PACKED_OUT)
        for (int k = 0; k < e; ++k) off += cnt[k];   // prefix base of expert e
    const int n0 = nb * 64;
    const int tid = threadIdx.x, lane = tid & 63, w = tid >> 6;
    const int wr = w & 1, wc = w >> 1;      // wave -> (row-half, col-half)
    const int l15 = lane & 15, q8 = (lane >> 4) * 8, q = lane >> 4;
    const int ar = tid >> 1, aseg = (tid & 1) * 32;   // A staging: 2 thr/row, 64B each
    const int wrow = tid >> 2, wsk = (tid & 3) * 16;  // W staging: 4 thr/row, 16 fl each

    const TW* bsrc = Wb + (size_t)e * DMODEL * DMODEL + (size_t)(n0 + wrow) * DMODEL + wsk;
    const int* lst = list + e * T_TOK;

    for (int yt = blockIdx.y; yt * BM < c; yt += 4) {
        const int m0 = yt * BM;
        __syncthreads();                     // prior y-iter epilogue done (LDS reuse)
        if (!PACKED_OUT && tid < BM) {
            int mi = m0 + tid;
            toks[tid] = lst[mi < c ? mi : c - 1];
        }
        const int ma0 = m0 + ar;
        const int mac = ma0 < c ? ma0 : c - 1;
        const unsigned short* asrc = PACKED_IN
            ? in + (size_t)(off + mac) * DMODEL + aseg
            : in + (size_t)lst[mac] * DMODEL + aseg;

        f32x4 acc[4][2];
#pragma unroll
        for (int i = 0; i < 4; ++i)
#pragma unroll
            for (int j = 0; j < 2; ++j) acc[i][j] = (f32x4){0.f, 0.f, 0.f, 0.f};

        uint4 pa[4];          // A: 4 uint4 = 64B (this thread's half-row)
        float4 fb[4];         // W fp32: 16 floats
        uint4 pbq[2];         // W bf16 (unused here; kept for symmetry)

        auto load_regs = [&](int k0) {
            const uint4* s = (const uint4*)(asrc + k0);
            pa[0] = s[0]; pa[1] = s[1]; pa[2] = s[2]; pa[3] = s[3];
            if constexpr (W_F32) {
                const float4* t2 = (const float4*)(bsrc + k0);
                fb[0] = t2[0]; fb[1] = t2[1]; fb[2] = t2[2]; fb[3] = t2[3];
            } else {
                const uint4* t2 = (const uint4*)(bsrc + k0);
                pbq[0] = t2[0]; pbq[1] = t2[1];
            }
        };
        auto store_tiles = [&](int buf) {
            *(uint4*)&At[buf][ar][aseg]      = pa[0];
            *(uint4*)&At[buf][ar][aseg + 8]  = pa[1];
            *(uint4*)&At[buf][ar][aseg + 16] = pa[2];
            *(uint4*)&At[buf][ar][aseg + 24] = pa[3];
            if constexpr (W_F32) {
                uint4 w0, w1;
                w0.x = pack2(fb[0].x, fb[0].y); w0.y = pack2(fb[0].z, fb[0].w);
                w0.z = pack2(fb[1].x, fb[1].y); w0.w = pack2(fb[1].z, fb[1].w);
                w1.x = pack2(fb[2].x, fb[2].y); w1.y = pack2(fb[2].z, fb[2].w);
                w1.z = pack2(fb[3].x, fb[3].y); w1.w = pack2(fb[3].z, fb[3].w);
                *(uint4*)&Bt[buf][wrow][wsk] = w0; *(uint4*)&Bt[buf][wrow][wsk + 8] = w1;
            } else {
                *(uint4*)&Bt[buf][wrow][wsk] = pbq[0];
                *(uint4*)&Bt[buf][wrow][wsk + 8] = pbq[1];
            }
        };

        load_regs(0);
        store_tiles(0);
#pragma unroll 1
        for (int it = 0; it < NIT; ++it) {
            __syncthreads();                 // buf[it&1] ready
            if (it + 1 < NIT) load_regs((it + 1) * BK);
            const int buf = it & 1;
#pragma unroll
            for (int kk = 0; kk < BK; kk += 32) {
                bf16x8 b0 = *(const bf16x8*)&Bt[buf][wc * 32 + l15][kk + q8];
                bf16x8 b1 = *(const bf16x8*)&Bt[buf][wc * 32 + 16 + l15][kk + q8];
#pragma unroll
                for (int i = 0; i < 4; ++i) {
                    bf16x8 ai = *(const bf16x8*)&At[buf][wr * 64 + i * 16 + l15][kk + q8];
                    acc[i][0] = __builtin_amdgcn_mfma_f32_16x16x32_bf16(b0, ai, acc[i][0], 0, 0, 0);
                    acc[i][1] = __builtin_amdgcn_mfma_f32_16x16x32_bf16(b1, ai, acc[i][1], 0, 0, 0);
                }
            }
            if (it + 1 < NIT) store_tiles(buf ^ 1);  // peers read buf only
        }

        // ---- staged epilogue: acc(+bias,+GELU) -> LDS C -> full-line stores
        __syncthreads();                     // all MFMA LDS reads done; overlay At
        float (*C)[68] = reinterpret_cast<float (*)[68]>(&At[0][0][0]);  // 34.8KB<=36.9
#pragma unroll
        for (int i = 0; i < 4; ++i) {
            const int mrow = wr * 64 + i * 16 + l15;
#pragma unroll
            for (int j = 0; j < 2; ++j) {
                const int lc = wc * 32 + j * 16 + q * 4;
                const float4 bv = *(const float4*)&bias[e * DMODEL + n0 + lc];
                float v0 = acc[i][j][0] + bv.x;
                float v1 = acc[i][j][1] + bv.y;
                float v2 = acc[i][j][2] + bv.z;
                float v3 = acc[i][j][3] + bv.w;
                if (GELU) {
                    v0 = 0.5f * v0 * (1.f + erff(v0 * 0.70710678118654752f));
                    v1 = 0.5f * v1 * (1.f + erff(v1 * 0.70710678118654752f));
                    v2 = 0.5f * v2 * (1.f + erff(v2 * 0.70710678118654752f));
                    v3 = 0.5f * v3 * (1.f + erff(v3 * 0.70710678118654752f));
                }
                *(float4*)&C[mrow][lc] = make_float4(v0, v1, v2, v3);
            }
        }
        __syncthreads();
        {   // thread -> (row, 32-col half): 2 adjacent lanes cover a row contiguously
            const int row = tid >> 1, half = (tid & 1) * 32;
            if (m0 + row < c) {
                const size_t rb = PACKED_OUT
                    ? (size_t)(off + m0 + row) * DMODEL
                    : (size_t)toks[row] * DMODEL;
                const float* cr = &C[row][half];
                if constexpr (std::is_same<TOUT, float>::value) {
                    float4* dst = (float4*)&outp[rb + n0 + half];
#pragma unroll
                    for (int u = 0; u < 8; ++u) dst[u] = *(const float4*)&cr[4 * u];
                } else {
                    uint4* dst = (uint4*)&outp[rb + n0 + half];
#pragma unroll
                    for (int u = 0; u < 4; ++u)
                        dst[u] = make_uint4(pack2(cr[8*u+0], cr[8*u+1]),
                                            pack2(cr[8*u+2], cr[8*u+3]),
                                            pack2(cr[8*u+4], cr[8*u+5]),
                                            pack2(cr[8*u+6], cr[8*u+7]));
                }
            }
        }
    }
}

// ---------- legacy small-workspace kernel (proven, fp32 A input) --------------------
template<int GELU, typename TA, typename TW, typename TOUT>
__global__ __launch_bounds__(256, 4) void expert_layer(
    const TA* __restrict__ in, const TW* __restrict__ W,
    const float* __restrict__ bias, const int* __restrict__ cnt,
    const int* __restrict__ list, TOUT* __restrict__ outp)
{
    constexpr int BK = 64, LDK = 72;
    constexpr bool A_F32 = std::is_same<TA, float>::value;
    constexpr bool W_F32 = std::is_same<TW, float>::value;
    __shared__ __align__(16) unsigned short At[2][64][LDK];
    __shared__ __align__(16) unsigned short Bt[2][64][LDK];
    __shared__ int toks[64];

    const int bx = blockIdx.x;
    const int e = bx / 12, nb = bx % 12;
    const int c = cnt[e];
    const int n0 = nb * 64;
    const int tid = threadIdx.x, lane = tid & 63, w = tid >> 6;
    const int rg = w & 1, cgp = w >> 1;
    const int l15 = lane & 15, q8 = (lane >> 4) * 8, q = lane >> 4;
    const int sr = tid >> 2, sk = (tid & 3) * 16;

    const TW* bsrc = W + (size_t)e * DMODEL * DMODEL + (size_t)(n0 + sr) * DMODEL + sk;
    const int* lst = list + e * T_TOK;

    uint4 pa[2], pb[2];
    float4 fa[4], fb[4];

    for (int yt = blockIdx.y; yt * 64 < c; yt += 8) {
        const int m0 = yt * 64;
        __syncthreads();
        if (tid < 64) {
            int mi = m0 + tid;
            toks[tid] = lst[mi < c ? mi : c - 1];
        }
        int ma = m0 + sr;
        const TA* asrc = in + (size_t)lst[ma < c ? ma : c - 1] * DMODEL + sk;

        f32x4 acc[2][2];
#pragma unroll
        for (int i = 0; i < 2; ++i)
#pragma unroll
            for (int j = 0; j < 2; ++j) acc[i][j] = (f32x4){0.f, 0.f, 0.f, 0.f};

        auto load_regs = [&](int k0) {
            if constexpr (A_F32) {
                const float4* s = (const float4*)(asrc + k0);
                fa[0] = s[0]; fa[1] = s[1]; fa[2] = s[2]; fa[3] = s[3];
            } else {
                const uint4* s = (const uint4*)(asrc + k0);
                pa[0] = s[0]; pa[1] = s[1];
            }
            if constexpr (W_F32) {
                const float4* s = (const float4*)(bsrc + k0);
                fb[0] = s[0]; fb[1] = s[1]; fb[2] = s[2]; fb[3] = s[3];
            } else {
                const uint4* s = (const uint4*)(bsrc + k0);
                pb[0] = s[0]; pb[1] = s[1];
            }
        };
        auto store_tiles = [&](int buf) {
            if constexpr (A_F32) {
                uint4 w0, w1;
                w0.x = pack2(fa[0].x, fa[0].y); w0.y = pack2(fa[0].z, fa[0].w);
                w0.z = pack2(fa[1].x, fa[1].y); w0.w = pack2(fa[1].z, fa[1].w);
                w1.x = pack2(fa[2].x, fa[2].y); w1.y = pack2(fa[2].z, fa[2].w);
                w1.z = pack2(fa[3].x, fa[3].y); w1.w = pack2(fa[3].z, fa[3].w);
                *(uint4*)&At[buf][sr][sk] = w0; *(uint4*)&At[buf][sr][sk + 8] = w1;
            } else {
                *(uint4*)&At[buf][sr][sk] = pa[0]; *(uint4*)&At[buf][sr][sk + 8] = pa[1];
            }
            if constexpr (W_F32) {
                uint4 w0, w1;
                w0.x = pack2(fb[0].x, fb[0].y); w0.y = pack2(fb[0].z, fb[0].w);
                w0.z = pack2(fb[1].x, fb[1].y); w0.w = pack2(fb[1].z, fb[1].w);
                w1.x = pack2(fb[2].x, fb[2].y); w1.y = pack2(fb[2].z, fb[2].w);
                w1.z = pack2(fb[3].x, fb[3].y); w1.w = pack2(fb[3].z, fb[3].w);
                *(uint4*)&Bt[buf][sr][sk] = w0; *(uint4*)&Bt[buf][sr][sk + 8] = w1;
            } else {
                *(uint4*)&Bt[buf][sr][sk] = pb[0]; *(uint4*)&Bt[buf][sr][sk + 8] = pb[1];
            }
        };

        load_regs(0);
        store_tiles(0);
#pragma unroll 1
        for (int it = 0; it < DMODEL / BK; ++it) {
            __syncthreads();
            if (it + 1 < DMODEL / BK) load_regs((it + 1) * BK);
            const int buf = it & 1;
#pragma unroll
            for (int kk = 0; kk < BK; kk += 32) {
                bf16x8 a0 = *(const bf16x8*)&At[buf][rg * 32 + l15][kk + q8];
                bf16x8 a1 = *(const bf16x8*)&At[buf][rg * 32 + 16 + l15][kk + q8];
                bf16x8 b0 = *(const bf16x8*)&Bt[buf][cgp * 32 + l15][kk + q8];
                bf16x8 b1 = *(const bf16x8*)&Bt[buf][cgp * 32 + 16 + l15][kk + q8];
                acc[0][0] = __builtin_amdgcn_mfma_f32_16x16x32_bf16(a0, b0, acc[0][0], 0, 0, 0);
                acc[0][1] = __builtin_amdgcn_mfma_f32_16x16x32_bf16(a0, b1, acc[0][1], 0, 0, 0);
                acc[1][0] = __builtin_amdgcn_mfma_f32_16x16x32_bf16(a1, b0, acc[1][0], 0, 0, 0);
                acc[1][1] = __builtin_amdgcn_mfma_f32_16x16x32_bf16(a1, b1, acc[1][1], 0, 0, 0);
            }
            if (it + 1 < DMODEL / BK) store_tiles(buf ^ 1);
        }

#pragma unroll
        for (int i = 0; i < 2; ++i) {
#pragma unroll
            for (int j = 0; j < 2; ++j) {
                int col = n0 + cgp * 32 + j * 16 + l15;
                float bv = bias[e * DMODEL + col];
#pragma unroll
                for (int r = 0; r < 4; ++r) {
                    int mrow = rg * 32 + i * 16 + q * 4 + r;
                    if (m0 + mrow < c) {
                        float val = acc[i][j][r] + bv;
                        if (GELU) val = 0.5f * val * (1.f + erff(val * 0.70710678118654752f));
                        size_t idx = (size_t)toks[mrow] * DMODEL + col;
                        if constexpr (std::is_same<TOUT, float>::value) outp[idx] = val;
                        else outp[idx] = f2bf(val);
                    }
                }
            }
        }
    }
}

// ---------- launch ------------------------------------------------------------------
extern "C" void kernel_launch(void* const* d_in, const int* in_sizes, int n_in,
                              void* d_out, int out_size, void* d_ws, size_t ws_size,
                              hipStream_t stream)
{
    const float* x  = (const float*)d_in[0];
    const float* W1 = (const float*)d_in[1];
    const float* b1 = (const float*)d_in[2];
    const float* W2 = (const float*)d_in[3];
    const float* b2 = (const float*)d_in[4];
    const float* Wg = (const float*)d_in[5];
    const float* bg = (const float*)d_in[6];
    float* out = (float*)d_out;

    char* ws   = (char*)d_ws;
    int*  cnt  = (int*)ws;                                  // 64 B
    int*  list = (int*)(ws + 256);                          // 403,456 B
    unsigned short* xb  = (unsigned short*)(ws + 403712);   // 9,682,944 B
    unsigned short* h   = (unsigned short*)(ws + 10086656); // 9,682,944 B
    const bool big = ws_size >= (size_t)19769600;

    hipMemsetAsync(cnt, 0, 256, stream);
    if (big) {
        gate_kernel<<<dim3(NGATE), dim3(256), 0, stream>>>(
            x, Wg, bg, cnt, list, xb);
        dim3 grid(12 * NEXP, 4);   // 192 x 4; BM=128 persistent y-stride
        // L1: gathered bf16 x @ fp32 W1 (in-reg convert) -> packed bf16 h
        expert_gemm<1, 0, 1, float, unsigned short>
            <<<grid, dim3(256), 0, stream>>>(xb, W1, b1, cnt, list, h);
        // L2: packed bf16 h @ fp32 W2 (in-reg convert) -> scattered fp32 out
        expert_gemm<0, 1, 0, float, float>
            <<<grid, dim3(256), 0, stream>>>(h, W2, b2, cnt, list, out);
    } else {   // fallback: fp32 A input with fused bf16 staging (proven path)
        gate_kernel<<<dim3(NGATE), dim3(256), 0, stream>>>(
            x, Wg, bg, cnt, list, nullptr);
        dim3 grid(12 * NEXP, 8);
        expert_layer<1, float, float, unsigned short>
            <<<grid, dim3(256), 0, stream>>>(x, W1, b1, cnt, list, h);
        expert_layer<0, unsigned short, float, float>
            <<<grid, dim3(256), 0, stream>>>(h, W2, b2, cnt, list, out);
    }
}